// Round 5
// baseline (393.652 us; speedup 1.0000x reference)
//
#include <hip/hip_runtime.h>

#define ISZ 10
#define HSZ 20
#define BSZ 4096
#define TSZ 512
#define BPW 3                          // batches per wave (20 lanes each, 4 idle)
#define NBLK ((BSZ + BPW - 1) / BPW)   // 1366 one-wave blocks

typedef __fp16 half2_t __attribute__((ext_vector_type(2)));

__device__ __forceinline__ float fdot2(half2_t a, half2_t b, float c) {
    return __builtin_amdgcn_fdot2(a, b, c, false);
}

__global__ __launch_bounds__(64) void lstm_fwd(
    const float* __restrict__ data, const float* __restrict__ Wih,
    const float* __restrict__ Whh, const float* __restrict__ bih,
    const float* __restrict__ bhh, float* __restrict__ partials)
{
    // 4 h-rows (f16), stride 32 halves = 64 B. Rows 0..2 real batches, row 3
    // trash for the 4 idle lanes. h-exchange uses VOLATILE ds ops only — no
    // "memory" clobber, so global-loaded weights stay register-resident.
    // DS ops from one wave execute in order -> write@step t visible to
    // reads@step t+1 without waitcnt/barrier (wave-synchronous idiom).
    __shared__ __align__(16) __fp16 hbuf[4 * 32];

    const int lane  = threadIdx.x;        // 0..63
    const int g     = lane / HSZ;         // batch group 0..3 (3 = idle lanes)
    const int j     = lane - g * HSZ;     // hidden unit 0..19
    const int batch = blockIdx.x * BPW + g;
    const bool active = (g < BPW) && (batch < BSZ);
    const int bl = active ? batch : 0;    // clamp for safe loads

    // Per-thread weight rows, f16-packed, with activation scale constants
    // folded in: sigmoid gates (i,f,o) scaled by -log2e, tanh gate (g) by
    // +2*log2e. Then ig=rcp(1+exp2(acc)), gg=1-2*rcp(1+exp2(acc)).
    // Gate order i,f,g,o -> rows j, j+20, j+40, j+60.
    const float sc[4] = {-1.44269504f, -1.44269504f, 2.88539008f, -1.44269504f};
    half2_t wih2[4][ISZ / 2], whh2[4][HSZ / 2];
    float bias[4];
#pragma unroll
    for (int q = 0; q < 4; ++q) {
        const int row = q * HSZ + j;
#pragma unroll
        for (int i = 0; i < ISZ / 2; ++i) {
            wih2[q][i].x = (__fp16)(sc[q] * Wih[row * ISZ + 2 * i]);
            wih2[q][i].y = (__fp16)(sc[q] * Wih[row * ISZ + 2 * i + 1]);
        }
#pragma unroll
        for (int k = 0; k < HSZ / 2; ++k) {
            whh2[q][k].x = (__fp16)(sc[q] * Whh[row * HSZ + 2 * k]);
            whh2[q][k].y = (__fp16)(sc[q] * Whh[row * HSZ + 2 * k + 1]);
        }
        bias[q] = sc[q] * (bih[row] + bhh[row]);
    }

    __fp16* hrow = &hbuf[g * 32];
    volatile __fp16* hw = hrow + j;                       // my h slot
    const volatile half2_t* hp = (const volatile half2_t*)hrow;

    // zero all rows fully (20 lanes/group write j, j+12, and j<8 write j+24)
    *hw = (__fp16)0.f;
    *(volatile __fp16*)(hrow + j + 12) = (__fp16)0.f;
    if (j < 8) *(volatile __fp16*)(hrow + j + 24) = (__fp16)0.f;

    float c = 0.0f, sum = 0.0f;
    const float* xbase = data + (size_t)bl * (TSZ * ISZ);

    half2_t xa[ISZ / 2], xb[ISZ / 2];

    auto loadx = [&](half2_t* dst, int t) {
        const float2* p = (const float2*)(xbase + t * ISZ);  // 8B-aligned (t*40B)
        float2 v0 = p[0], v1 = p[1], v2 = p[2], v3 = p[3], v4 = p[4];
        dst[0] = __builtin_amdgcn_cvt_pkrtz(v0.x, v0.y);
        dst[1] = __builtin_amdgcn_cvt_pkrtz(v1.x, v1.y);
        dst[2] = __builtin_amdgcn_cvt_pkrtz(v2.x, v2.y);
        dst[3] = __builtin_amdgcn_cvt_pkrtz(v3.x, v3.y);
        dst[4] = __builtin_amdgcn_cvt_pkrtz(v4.x, v4.y);
    };

    auto step = [&](const half2_t* x) {
        // volatile h read: 5x ds_read_b32, re-read each step by construction
        half2_t h2[HSZ / 2];
#pragma unroll
        for (int k = 0; k < HSZ / 2; ++k) h2[k] = hp[k];

        // 3 independent sub-chains per gate (x, h-low, h-high): dep depth <=5
        float acc[4];
#pragma unroll
        for (int q = 0; q < 4; ++q) {
            float ax = bias[q], al = 0.0f, ah = 0.0f;
#pragma unroll
            for (int i = 0; i < ISZ / 2; ++i) ax = fdot2(wih2[q][i], x[i], ax);
#pragma unroll
            for (int k = 0; k < 5; ++k) al = fdot2(whh2[q][k], h2[k], al);
#pragma unroll
            for (int k = 5; k < 10; ++k) ah = fdot2(whh2[q][k], h2[k], ah);
            acc[q] = ax + (al + ah);
        }
        // scales pre-folded: sigmoid = rcp(1+exp2(acc)); tanh = 1-2*rcp(1+exp2(acc))
        float ig = __builtin_amdgcn_rcpf(1.0f + __builtin_amdgcn_exp2f(acc[0]));
        float fg = __builtin_amdgcn_rcpf(1.0f + __builtin_amdgcn_exp2f(acc[1]));
        float gg = 1.0f - 2.0f * __builtin_amdgcn_rcpf(1.0f + __builtin_amdgcn_exp2f(acc[2]));
        float og = __builtin_amdgcn_rcpf(1.0f + __builtin_amdgcn_exp2f(acc[3]));
        c = fg * c + ig * gg;
        float tc = 1.0f - 2.0f * __builtin_amdgcn_rcpf(1.0f + __builtin_amdgcn_exp2f(2.88539008f * c));
        float hn = og * tc;
        sum += hn;
        *hw = (__fp16)hn;   // volatile ds_write_b16; in-order DS pipe per wave
    };

    loadx(xa, 0);
    for (int t = 0; t < TSZ; t += 2) {
        loadx(xb, t + 1);                 // prefetch: latency hides under step(xa)
        step(xa);
        const int t2 = (t + 2 < TSZ) ? (t + 2) : (TSZ - 1);
        loadx(xa, t2);                    // prefetch next pair (last iter: harmless reload)
        step(xb);
    }

    if (!active) sum = 0.0f;
#pragma unroll
    for (int off = 32; off > 0; off >>= 1) sum += __shfl_down(sum, off, 64);
    if (lane == 0) partials[blockIdx.x] = sum;
}

__global__ __launch_bounds__(1024) void reduce_partials(
    const float* __restrict__ partials, float* __restrict__ out)
{
    float s = 0.0f;
    for (int i = threadIdx.x; i < NBLK; i += 1024) s += partials[i];
#pragma unroll
    for (int off = 32; off > 0; off >>= 1) s += __shfl_down(s, off, 64);
    __shared__ float wsum[16];
    const int w = threadIdx.x >> 6;
    if ((threadIdx.x & 63) == 0) wsum[w] = s;
    __syncthreads();
    if (threadIdx.x < 16) {
        float v = wsum[threadIdx.x];
#pragma unroll
        for (int off = 8; off > 0; off >>= 1) v += __shfl_down(v, off, 64);
        if (threadIdx.x == 0) out[0] = v;
    }
}

extern "C" void kernel_launch(void* const* d_in, const int* in_sizes, int n_in,
                              void* d_out, int out_size, void* d_ws, size_t ws_size,
                              hipStream_t stream) {
    const float* data = (const float*)d_in[0];
    const float* Wih  = (const float*)d_in[1];
    const float* Whh  = (const float*)d_in[2];
    const float* bih  = (const float*)d_in[3];
    const float* bhh  = (const float*)d_in[4];
    float* out        = (float*)d_out;
    float* partials   = (float*)d_ws;   // NBLK floats, fully written every launch

    lstm_fwd<<<NBLK, 64, 0, stream>>>(data, Wih, Whh, bih, bhh, partials);
    reduce_partials<<<1, 1024, 0, stream>>>(partials, out);
}

// Round 6
// 241.959 us; speedup vs baseline: 1.6269x; 1.6269x over previous
//
#include <hip/hip_runtime.h>
#include <stdint.h>

#define ISZ 10
#define HSZ 20
#define BSZ 4096
#define TSZ 512
#define BPW 3                          // batches per wave (20 lanes each, 4 idle)
#define NBLK ((BSZ + BPW - 1) / BPW)   // 1366 one-wave blocks

typedef __fp16 half2_t __attribute__((ext_vector_type(2)));

__device__ __forceinline__ float fdot2(half2_t a, half2_t b, float c) {
    return __builtin_amdgcn_fdot2(a, b, c, false);
}

// Pin a 4-byte value into a VGPR as an opaque SSA def: the loop can no longer
// "rematerialize" it by re-loading from global memory.
__device__ __forceinline__ void pin(half2_t& v) {
    uint32_t u = __builtin_bit_cast(uint32_t, v);
    asm("" : "+v"(u));
    v = __builtin_bit_cast(half2_t, u);
}
__device__ __forceinline__ void pinf(float& v) { asm("" : "+v"(v)); }

__global__ __launch_bounds__(64, 2) void lstm_fwd(
    const float* __restrict__ data, const float* __restrict__ Wih,
    const float* __restrict__ Whh, const float* __restrict__ bih,
    const float* __restrict__ bhh, float* __restrict__ partials)
{
    // 4 h-rows (f16), stride 32 halves = 64 B. Rows 0..2 real batches, row 3
    // trash for the 4 idle lanes. Wave-synchronous exchange: ds ops of one
    // wave execute in order; the "memory" clobber stops compiler caching.
    __shared__ __align__(16) __fp16 hbuf[4 * 32];

    const int lane  = threadIdx.x;        // 0..63
    const int g     = lane / HSZ;         // batch group 0..3 (3 = idle lanes)
    const int j     = lane - g * HSZ;     // hidden unit 0..19
    const int batch = blockIdx.x * BPW + g;
    const bool active = (g < BPW) && (batch < BSZ);
    const int bl = active ? batch : 0;    // clamp for safe loads

    // Per-thread weight rows, f16-packed, activation scale constants folded:
    // sigmoid gates (i,f,o) scaled by -log2e, tanh gate (g) by +2*log2e.
    // Gate order i,f,g,o -> rows j, j+20, j+40, j+60.
    const float sc[4] = {-1.44269504f, -1.44269504f, 2.88539008f, -1.44269504f};
    half2_t wih2[4][ISZ / 2], whh2[4][HSZ / 2];
    float bias[4];
#pragma unroll
    for (int q = 0; q < 4; ++q) {
        const int row = q * HSZ + j;
#pragma unroll
        for (int i = 0; i < ISZ / 2; ++i) {
            wih2[q][i].x = (__fp16)(sc[q] * Wih[row * ISZ + 2 * i]);
            wih2[q][i].y = (__fp16)(sc[q] * Wih[row * ISZ + 2 * i + 1]);
        }
#pragma unroll
        for (int k = 0; k < HSZ / 2; ++k) {
            whh2[q][k].x = (__fp16)(sc[q] * Whh[row * HSZ + 2 * k]);
            whh2[q][k].y = (__fp16)(sc[q] * Whh[row * HSZ + 2 * k + 1]);
        }
        bias[q] = sc[q] * (bih[row] + bhh[row]);
    }
    // Force register residency of all loop-invariant operands.
#pragma unroll
    for (int q = 0; q < 4; ++q) {
#pragma unroll
        for (int i = 0; i < ISZ / 2; ++i) pin(wih2[q][i]);
#pragma unroll
        for (int k = 0; k < HSZ / 2; ++k) pin(whh2[q][k]);
        pinf(bias[q]);
    }

    __fp16* hrow = &hbuf[g * 32];
    // zero all rows fully (20 lanes/group write j, j+12, and j<8 write j+24)
    hrow[j] = (__fp16)0.f;
    if (j < 12) hrow[j + 12] = (__fp16)0.f;
    if (j < 8)  hrow[j + 24] = (__fp16)0.f;
    asm volatile("" ::: "memory");

    float c = 0.0f, sum = 0.0f;
    const float* xbase = data + (size_t)bl * (TSZ * ISZ);

    half2_t xa[ISZ / 2], xb[ISZ / 2];

    auto loadx = [&](half2_t* dst, int t) {
        const float2* p = (const float2*)(xbase + t * ISZ);  // 8B-aligned (t*40B)
        float2 v0 = p[0], v1 = p[1], v2 = p[2], v3 = p[3], v4 = p[4];
        dst[0] = __builtin_amdgcn_cvt_pkrtz(v0.x, v0.y);
        dst[1] = __builtin_amdgcn_cvt_pkrtz(v1.x, v1.y);
        dst[2] = __builtin_amdgcn_cvt_pkrtz(v2.x, v2.y);
        dst[3] = __builtin_amdgcn_cvt_pkrtz(v3.x, v3.y);
        dst[4] = __builtin_amdgcn_cvt_pkrtz(v4.x, v4.y);
    };

    auto step = [&](const half2_t* x) {
        // vectorized h read (b128+b64); re-read each step forced by the clobber
        half2_t h2[HSZ / 2];
        const half2_t* hp = (const half2_t*)__builtin_assume_aligned(hrow, 16);
#pragma unroll
        for (int k = 0; k < HSZ / 2; ++k) h2[k] = hp[k];

        // 3 independent sub-chains per gate (x, h-low, h-high): dep depth <=5
        float acc[4];
#pragma unroll
        for (int q = 0; q < 4; ++q) {
            float ax = bias[q], al = 0.0f, ah = 0.0f;
#pragma unroll
            for (int i = 0; i < ISZ / 2; ++i) ax = fdot2(wih2[q][i], x[i], ax);
#pragma unroll
            for (int k = 0; k < 5; ++k) al = fdot2(whh2[q][k], h2[k], al);
#pragma unroll
            for (int k = 5; k < 10; ++k) ah = fdot2(whh2[q][k], h2[k], ah);
            acc[q] = ax + (al + ah);
        }
        // scales pre-folded: sigmoid = rcp(1+exp2(acc)); tanh = 1-2*rcp(1+exp2(acc))
        float ig = __builtin_amdgcn_rcpf(1.0f + __builtin_amdgcn_exp2f(acc[0]));
        float fg = __builtin_amdgcn_rcpf(1.0f + __builtin_amdgcn_exp2f(acc[1]));
        float gg = 1.0f - 2.0f * __builtin_amdgcn_rcpf(1.0f + __builtin_amdgcn_exp2f(acc[2]));
        float og = __builtin_amdgcn_rcpf(1.0f + __builtin_amdgcn_exp2f(acc[3]));
        c = fg * c + ig * gg;
        float tc = 1.0f - 2.0f * __builtin_amdgcn_rcpf(1.0f + __builtin_amdgcn_exp2f(2.88539008f * c));
        float hn = og * tc;
        sum += hn;
        hrow[j] = (__fp16)hn;
        asm volatile("" ::: "memory");  // force LDS re-read next step (wave-sync idiom)
    };

    loadx(xa, 0);
    for (int t = 0; t < TSZ; t += 2) {
        loadx(xb, t + 1);                 // prefetch: latency hides under step(xa)
        step(xa);
        const int t2 = (t + 2 < TSZ) ? (t + 2) : (TSZ - 1);
        loadx(xa, t2);                    // prefetch next pair (last iter: harmless reload)
        step(xb);
    }

    if (!active) sum = 0.0f;
#pragma unroll
    for (int off = 32; off > 0; off >>= 1) sum += __shfl_down(sum, off, 64);
    if (lane == 0) partials[blockIdx.x] = sum;
}

__global__ __launch_bounds__(1024) void reduce_partials(
    const float* __restrict__ partials, float* __restrict__ out)
{
    float s = 0.0f;
    for (int i = threadIdx.x; i < NBLK; i += 1024) s += partials[i];
#pragma unroll
    for (int off = 32; off > 0; off >>= 1) s += __shfl_down(s, off, 64);
    __shared__ float wsum[16];
    const int w = threadIdx.x >> 6;
    if ((threadIdx.x & 63) == 0) wsum[w] = s;
    __syncthreads();
    if (threadIdx.x < 16) {
        float v = wsum[threadIdx.x];
#pragma unroll
        for (int off = 8; off > 0; off >>= 1) v += __shfl_down(v, off, 64);
        if (threadIdx.x == 0) out[0] = v;
    }
}

extern "C" void kernel_launch(void* const* d_in, const int* in_sizes, int n_in,
                              void* d_out, int out_size, void* d_ws, size_t ws_size,
                              hipStream_t stream) {
    const float* data = (const float*)d_in[0];
    const float* Wih  = (const float*)d_in[1];
    const float* Whh  = (const float*)d_in[2];
    const float* bih  = (const float*)d_in[3];
    const float* bhh  = (const float*)d_in[4];
    float* out        = (float*)d_out;
    float* partials   = (float*)d_ws;   // NBLK floats, fully written every launch

    lstm_fwd<<<NBLK, 64, 0, stream>>>(data, Wih, Whh, bih, bhh, partials);
    reduce_partials<<<1, 1024, 0, stream>>>(partials, out);
}